// Round 6
// baseline (504.421 us; speedup 1.0000x reference)
//
#include <hip/hip_runtime.h>
#include <cmath>

#define NK 1024
#define ND 64
#define NB 32
#define NH 64
#define NW 64
#define NTOT (NB*NH*NW)   // 131072 query vectors

// d_ws layout: [0..1023] uint32 counts, [1024..2047] float cnorm

__global__ __launch_bounds__(1024) void vq_prep(const float* __restrict__ emb,
                                                unsigned int* __restrict__ counts,
                                                float* __restrict__ cnorm) {
    int k = threadIdx.x;  // 1024 threads, one per code
    counts[k] = 0u;
    const float4* row = reinterpret_cast<const float4*>(emb + (size_t)k * ND);
    float s = 0.0f;
#pragma unroll
    for (int i = 0; i < ND/4; ++i) {
        float4 v = row[i];
        s += v.x*v.x + v.y*v.y + v.z*v.z + v.w*v.w;
    }
    cnorm[k] = s;
}

// 8x8 register micro-tile; block = 128 queries x 128-code chunks.
// Loop bodies kept under the 32KB L1I: chunk loop and outer-d4 loop are
// `unroll 1`; only 4 d4-steps (~9KB) unrolled inside.
__global__ __launch_bounds__(256, 2) void vq_main(const float* __restrict__ in,
                                                  const float* __restrict__ emb,
                                                  const float* __restrict__ cnorm,
                                                  unsigned int* __restrict__ counts,
                                                  float* __restrict__ out_idx,
                                                  float* __restrict__ out_q) {
    __shared__ float Xs[128][68];   // pad 68: 4-bank row stride, b128 16B-aligned
    __shared__ float Es[128][68];   // Es[kl][64] = cnorm[kc+kl]
    __shared__ int bidx_lds[128];

    const int blk = blockIdx.x;     // b*32 + h2 ; block covers h = 2*h2, 2*h2+1
    const int b   = blk >> 5;
    const int h0  = (blk & 31) << 1;
    const int tid = threadIdx.x;
    const int tk  = tid & 15;       // code group  (16)
    const int tq  = tid >> 4;       // query group (16)

    // ---- stage X: Xs[hl*64+w][c] = in[b, c, h0+hl, w] ----
    const float* inb = in + ((size_t)b << 18) + ((size_t)h0 << 6);
#pragma unroll
    for (int p = 0; p < 32; ++p) {
        int f = p * 256 + tid;      // f = c*128 + (hl*64+w); lanes -> consecutive w
        Xs[f & 127][f >> 7] = inb[(size_t)(f >> 7) * 4096 + (f & 127)];
    }

    float bestm[8];
    int   bi[8];
#pragma unroll
    for (int i = 0; i < 8; ++i) { bestm[i] = -3.4e38f; bi[i] = 0; }

#pragma unroll 1
    for (int ch = 0; ch < 8; ++ch) {
        const int kc = ch << 7;
        // ---- stage 128-code chunk (float4-coalesced) + cnorm in pad col ----
        {
            const int d4  = (tid & 15) << 2;
            const int kl0 = tid >> 4;
#pragma unroll
            for (int p = 0; p < 8; ++p) {
                int kl = kl0 + (p << 4);
                *reinterpret_cast<float4*>(&Es[kl][d4]) =
                    *reinterpret_cast<const float4*>(emb + ((size_t)(kc + kl) << 6) + d4);
            }
            if (tid < 128) Es[tid][64] = cnorm[kc + tid];
        }
        __syncthreads();

        float dot[8][8];
#pragma unroll
        for (int i = 0; i < 8; ++i)
#pragma unroll
            for (int j = 0; j < 8; ++j) dot[i][j] = 0.0f;

#pragma unroll 1
        for (int dd = 0; dd < 4; ++dd) {
#pragma unroll
            for (int d4i = 0; d4i < 4; ++d4i) {
                const int d4 = (dd << 4) + (d4i << 2);
                float4 xq[8], ek[8];
#pragma unroll
                for (int i = 0; i < 8; ++i)
                    xq[i] = *reinterpret_cast<const float4*>(&Xs[tq + (i << 4)][d4]);
#pragma unroll
                for (int j = 0; j < 8; ++j)
                    ek[j] = *reinterpret_cast<const float4*>(&Es[tk + (j << 4)][d4]);
#pragma unroll
                for (int i = 0; i < 8; ++i)
#pragma unroll
                    for (int j = 0; j < 8; ++j) {
                        dot[i][j] = fmaf(xq[i].x, ek[j].x, dot[i][j]);
                        dot[i][j] = fmaf(xq[i].y, ek[j].y, dot[i][j]);
                        dot[i][j] = fmaf(xq[i].z, ek[j].z, dot[i][j]);
                        dot[i][j] = fmaf(xq[i].w, ek[j].w, dot[i][j]);
                    }
            }
        }

        // ---- m = dot - cn/2 (maximize == argmin dist); k ascending per lane ----
#pragma unroll
        for (int j = 0; j < 8; ++j) {
            const int k = kc + tk + (j << 4);
            const float cn = Es[tk + (j << 4)][64];
#pragma unroll
            for (int i = 0; i < 8; ++i) {
                float m = fmaf(cn, -0.5f, dot[i][j]);
                if (m > bestm[i]) { bestm[i] = m; bi[i] = k; }  // strict > = first-min
            }
        }
        __syncthreads();  // before next chunk overwrites Es
    }

    // ---- reduce over the 16 tk lanes sharing each query ----
#pragma unroll
    for (int mm = 1; mm < 16; mm <<= 1) {
#pragma unroll
        for (int i = 0; i < 8; ++i) {
            float ob = __shfl_xor(bestm[i], mm, 64);
            int   oi = __shfl_xor(bi[i],   mm, 64);
            if (ob > bestm[i] || (ob == bestm[i] && oi < bi[i])) { bestm[i] = ob; bi[i] = oi; }
        }
    }
    if (tk == 0) {
#pragma unroll
        for (int i = 0; i < 8; ++i) bidx_lds[tq + (i << 4)] = bi[i];
    }
    __syncthreads();

    // ---- indices (as float) + histogram ----
    if (tid < 128) {
        int idx = bidx_lds[tid];
        out_idx[((size_t)b << 12) + ((size_t)h0 << 6) + tid] = (float)idx;
        atomicAdd(&counts[idx], 1u);
    }

    // ---- quantized (B,C,H,W): gather emb rows (L2-hot), coalesced stores ----
    float* outb = out_q + ((size_t)b << 18) + ((size_t)h0 << 6);
#pragma unroll
    for (int p = 0; p < 32; ++p) {
        int f  = p * 256 + tid;
        int c  = f >> 7;
        int ql = f & 127;
        outb[(size_t)c * 4096 + ql] = emb[((size_t)bidx_lds[ql] << 6) + c];
    }
}

__global__ __launch_bounds__(1024) void vq_perp(const unsigned int* __restrict__ counts,
                                                float* __restrict__ out_p) {
    __shared__ float red[16];
    int tid = threadIdx.x;  // 1024
    float p = (float)counts[tid] * (1.0f / (float)NTOT);
    float t = p * logf(p + 1e-10f);
#pragma unroll
    for (int m = 1; m < 64; m <<= 1) t += __shfl_xor(t, m, 64);
    if ((tid & 63) == 0) red[tid >> 6] = t;
    __syncthreads();
    if (tid < 16) {
        float s = red[tid];
#pragma unroll
        for (int m = 1; m < 16; m <<= 1) s += __shfl_xor(s, m, 64);
        if (tid == 0) out_p[0] = expf(-s);
    }
}

extern "C" void kernel_launch(void* const* d_in, const int* in_sizes, int n_in,
                              void* d_out, int out_size, void* d_ws, size_t ws_size,
                              hipStream_t stream) {
    const float* in  = (const float*)d_in[0];   // (32, 64, 64, 64)
    const float* emb = (const float*)d_in[1];   // (1024, 64)
    float* out = (float*)d_out;

    unsigned int* counts = (unsigned int*)d_ws;
    float* cnorm = (float*)d_ws + NK;

    float* out_idx = out;                       // 131072
    float* out_q   = out + NTOT;                // 8388608
    float* out_p   = out + NTOT + (size_t)NTOT * ND;  // 1

    vq_prep<<<1, 1024, 0, stream>>>(emb, counts, cnorm);
    vq_main<<<NTOT/128, 256, 0, stream>>>(in, emb, cnorm, counts, out_idx, out_q);
    vq_perp<<<1, 1024, 0, stream>>>(counts, out_p);
}

// Round 7
// 336.211 us; speedup vs baseline: 1.5003x; 1.5003x over previous
//
#include <hip/hip_runtime.h>
#include <cmath>

#define NK 1024
#define ND 64
#define NB 32
#define NH 64
#define NW 64
#define NTOT (NB*NH*NW)   // 131072 query vectors

// d_ws layout: [0..1023] uint32 counts, [1024..2047] float cnorm

__global__ __launch_bounds__(1024) void vq_prep(const float* __restrict__ emb,
                                                unsigned int* __restrict__ counts,
                                                float* __restrict__ cnorm) {
    int k = threadIdx.x;  // 1024 threads, one per code
    counts[k] = 0u;
    const float4* row = reinterpret_cast<const float4*>(emb + (size_t)k * ND);
    float s = 0.0f;
#pragma unroll
    for (int i = 0; i < ND/4; ++i) {
        float4 v = row[i];
        s += v.x*v.x + v.y*v.y + v.z*v.z + v.w*v.w;
    }
    cnorm[k] = s;
}

// 8x4 register micro-tile: 32 accumulators (no spill), 18KB chunk body (fits
// I$), LDS traffic 12.9GB (0.75x of round-2's 17.2GB). Block = 128 queries,
// 16 chunks of 64 codes.
__global__ __launch_bounds__(256, 2) void vq_main(const float* __restrict__ in,
                                                  const float* __restrict__ emb,
                                                  const float* __restrict__ cnorm,
                                                  unsigned int* __restrict__ counts,
                                                  float* __restrict__ out_idx,
                                                  float* __restrict__ out_q) {
    __shared__ float Xs[128][68];   // pad 68: 4-bank row stride, b128 16B-aligned
    __shared__ float Es[64][68];    // Es[kl][64] = cnorm[kc+kl]
    __shared__ int bidx_lds[128];

    const int blk = blockIdx.x;     // b*32 + h2 ; block covers h = 2*h2, 2*h2+1
    const int b   = blk >> 5;
    const int h0  = (blk & 31) << 1;
    const int tid = threadIdx.x;
    const int tk  = tid & 15;       // code group  (16 groups x Tk=4)
    const int tq  = tid >> 4;       // query group (16 groups x Tq=8)

    // ---- stage X: Xs[hl*64+w][c] = in[b, c, h0+hl, w] ----
    const float* inb = in + ((size_t)b << 18) + ((size_t)h0 << 6);
#pragma unroll
    for (int p = 0; p < 32; ++p) {
        int f = p * 256 + tid;      // f = c*128 + (hl*64+w); lanes -> consecutive w
        Xs[f & 127][f >> 7] = inb[(size_t)(f >> 7) * 4096 + (f & 127)];
    }

    float bestm[8];
    int   bi[8];
#pragma unroll
    for (int i = 0; i < 8; ++i) { bestm[i] = -3.4e38f; bi[i] = 0; }

#pragma unroll 1
    for (int ch = 0; ch < 16; ++ch) {
        const int kc = ch << 6;
        // ---- stage 64-code chunk (float4-coalesced) + cnorm in pad col ----
        {
            const int d4  = (tid & 15) << 2;
            const int kl0 = tid >> 4;
#pragma unroll
            for (int p = 0; p < 4; ++p) {
                int kl = kl0 + (p << 4);
                *reinterpret_cast<float4*>(&Es[kl][d4]) =
                    *reinterpret_cast<const float4*>(emb + ((size_t)(kc + kl) << 6) + d4);
            }
            if (tid < 64) Es[tid][64] = cnorm[kc + tid];
        }
        __syncthreads();

        float dot[8][4];
#pragma unroll
        for (int i = 0; i < 8; ++i)
#pragma unroll
            for (int j = 0; j < 4; ++j) dot[i][j] = 0.0f;

#pragma unroll
        for (int d4 = 0; d4 < 64; d4 += 4) {
            float4 xq[8], ek[4];
#pragma unroll
            for (int i = 0; i < 8; ++i)
                xq[i] = *reinterpret_cast<const float4*>(&Xs[tq + (i << 4)][d4]);
#pragma unroll
            for (int j = 0; j < 4; ++j)
                ek[j] = *reinterpret_cast<const float4*>(&Es[tk + (j << 4)][d4]);
#pragma unroll
            for (int i = 0; i < 8; ++i)
#pragma unroll
                for (int j = 0; j < 4; ++j) {
                    dot[i][j] = fmaf(xq[i].x, ek[j].x, dot[i][j]);
                    dot[i][j] = fmaf(xq[i].y, ek[j].y, dot[i][j]);
                    dot[i][j] = fmaf(xq[i].z, ek[j].z, dot[i][j]);
                    dot[i][j] = fmaf(xq[i].w, ek[j].w, dot[i][j]);
                }
        }

        // ---- m = dot - cn/2 (maximize == argmin dist); k ascending per lane ----
#pragma unroll
        for (int j = 0; j < 4; ++j) {
            const int k = kc + tk + (j << 4);
            const float cn = Es[tk + (j << 4)][64];
#pragma unroll
            for (int i = 0; i < 8; ++i) {
                float m = fmaf(cn, -0.5f, dot[i][j]);
                if (m > bestm[i]) { bestm[i] = m; bi[i] = k; }  // strict > = first-min
            }
        }
        __syncthreads();  // before next chunk overwrites Es
    }

    // ---- reduce over the 16 tk lanes sharing each query ----
#pragma unroll
    for (int mm = 1; mm < 16; mm <<= 1) {
#pragma unroll
        for (int i = 0; i < 8; ++i) {
            float ob = __shfl_xor(bestm[i], mm, 64);
            int   oi = __shfl_xor(bi[i],   mm, 64);
            if (ob > bestm[i] || (ob == bestm[i] && oi < bi[i])) { bestm[i] = ob; bi[i] = oi; }
        }
    }
    if (tk == 0) {
#pragma unroll
        for (int i = 0; i < 8; ++i) bidx_lds[tq + (i << 4)] = bi[i];
    }
    __syncthreads();

    // ---- indices (as float) + histogram ----
    if (tid < 128) {
        int idx = bidx_lds[tid];
        out_idx[((size_t)b << 12) + ((size_t)h0 << 6) + tid] = (float)idx;
        atomicAdd(&counts[idx], 1u);
    }

    // ---- quantized (B,C,H,W): gather emb rows (L2-hot), coalesced stores ----
    float* outb = out_q + ((size_t)b << 18) + ((size_t)h0 << 6);
#pragma unroll
    for (int p = 0; p < 32; ++p) {
        int f  = p * 256 + tid;
        int c  = f >> 7;
        int ql = f & 127;
        outb[(size_t)c * 4096 + ql] = emb[((size_t)bidx_lds[ql] << 6) + c];
    }
}

__global__ __launch_bounds__(1024) void vq_perp(const unsigned int* __restrict__ counts,
                                                float* __restrict__ out_p) {
    __shared__ float red[16];
    int tid = threadIdx.x;  // 1024
    float p = (float)counts[tid] * (1.0f / (float)NTOT);
    float t = p * logf(p + 1e-10f);
#pragma unroll
    for (int m = 1; m < 64; m <<= 1) t += __shfl_xor(t, m, 64);
    if ((tid & 63) == 0) red[tid >> 6] = t;
    __syncthreads();
    if (tid < 16) {
        float s = red[tid];
#pragma unroll
        for (int m = 1; m < 16; m <<= 1) s += __shfl_xor(s, m, 64);
        if (tid == 0) out_p[0] = expf(-s);
    }
}

extern "C" void kernel_launch(void* const* d_in, const int* in_sizes, int n_in,
                              void* d_out, int out_size, void* d_ws, size_t ws_size,
                              hipStream_t stream) {
    const float* in  = (const float*)d_in[0];   // (32, 64, 64, 64)
    const float* emb = (const float*)d_in[1];   // (1024, 64)
    float* out = (float*)d_out;

    unsigned int* counts = (unsigned int*)d_ws;
    float* cnorm = (float*)d_ws + NK;

    float* out_idx = out;                       // 131072
    float* out_q   = out + NTOT;                // 8388608
    float* out_p   = out + NTOT + (size_t)NTOT * ND;  // 1

    vq_prep<<<1, 1024, 0, stream>>>(emb, counts, cnorm);
    vq_main<<<NTOT/128, 256, 0, stream>>>(in, emb, cnorm, counts, out_idx, out_q);
    vq_perp<<<1, 1024, 0, stream>>>(counts, out_p);
}

// Round 8
// 114.694 us; speedup vs baseline: 4.3980x; 2.9314x over previous
//
#include <hip/hip_runtime.h>
#include <cmath>

typedef _Float16 f16;
typedef _Float16 f16x8 __attribute__((ext_vector_type(8)));
typedef float    f32x16 __attribute__((ext_vector_type(16)));

#define NK 1024
#define ND 64
#define NTOT 131072

// d_ws layout: [0..1023] u32 counts; [1024..2047] f32 g[k] = -0.5*||e_k||^2

__global__ __launch_bounds__(1024) void vq_prep(const float* __restrict__ emb,
                                                unsigned int* __restrict__ counts,
                                                float* __restrict__ g) {
    int k = threadIdx.x;
    counts[k] = 0u;
    const float4* row = reinterpret_cast<const float4*>(emb + (size_t)k * ND);
    float s = 0.0f;
#pragma unroll
    for (int i = 0; i < ND/4; ++i) {
        float4 v = row[i];
        s += v.x*v.x + v.y*v.y + v.z*v.z + v.w*v.w;
    }
    g[k] = -0.5f * s;
}

// fp16 double-split MFMA distance kernel.
// dot(x,e) = A0 + A1*2^-11 + A2*2^-22 with
//   A0 = xh.eh ; A1 = xh.el' + xl'.eh ; A2 = xl'.el'   (lo parts pre-scaled 2048)
// Per wave: 32 queries (B-frags persistent in VGPRs) vs all codes, 32 at a time.
__global__ __launch_bounds__(512, 2) void vq_main(const float* __restrict__ in,
                                                  const float* __restrict__ emb,
                                                  const float* __restrict__ g,
                                                  unsigned int* __restrict__ counts,
                                                  float* __restrict__ out_idx,
                                                  float* __restrict__ out_q) {
    __shared__ f16x8 Ef[2048];   // 32KB: frag(tt,u,lane) at Ef[(tt*8+u)*64+lane]
    __shared__ float gs[128];

    const int tid  = threadIdx.x;
    const int lane = tid & 63;
    const int wv   = tid >> 6;      // 0..7
    const int col  = lane & 31;     // this lane's query column
    const int hi   = lane >> 5;     // k-octet selector

    const int task = blockIdx.x * 8 + wv;   // 0..4095, 32 queries each
    const int q0   = task << 5;
    const int b    = q0 >> 12;
    const int hw0  = q0 & 4095;             // h*64 + w0
    const int q    = q0 + col;

    // ---- load my query column, build B-frags (xh, xl' = (x-xh)*2048) ----
    const float* xb = in + ((size_t)b << 18) + hw0 + col;   // + d*4096
    f16x8 xh[4], xl[4];
#pragma unroll
    for (int s = 0; s < 4; ++s) {
#pragma unroll
        for (int j = 0; j < 8; ++j) {
            float xv = xb[(size_t)(s*16 + hi*8 + j) << 12];
            f16 h = (f16)xv;
            xh[s][j] = h;
            xl[s][j] = (f16)((xv - (float)h) * 2048.0f);
        }
    }

    float bestm  = -3.4e38f;
    int   bestk  = 0;
    const float c1 = 4.8828125e-4f;           // 2^-11
    const float c2 = 2.384185791015625e-7f;   // 2^-22

#pragma unroll 1
    for (int cc = 0; cc < 8; ++cc) {
        // ---- stage 128 codes: split to (eh, el') in frag order ----
#pragma unroll
        for (int i = 0; i < 2; ++i) {
            int pi = tid*2 + i;            // 0..1023
            int tt = pi >> 8;
            int u4 = (pi >> 6) & 3;
            int ln = pi & 63;
            int c  = (((cc << 2) + tt) << 5) + (ln & 31);
            int d  = u4*16 + (ln >> 5)*8;
            const float4* src = reinterpret_cast<const float4*>(emb + ((size_t)c << 6) + d);
            float4 va = src[0], vb = src[1];
            float xs0[8] = {va.x, va.y, va.z, va.w, vb.x, vb.y, vb.z, vb.w};
            f16x8 vh, vl;
#pragma unroll
            for (int j = 0; j < 8; ++j) {
                f16 h = (f16)xs0[j];
                vh[j] = h;
                vl[j] = (f16)((xs0[j] - (float)h) * 2048.0f);
            }
            Ef[(tt*8 + u4    )*64 + ln] = vh;
            Ef[(tt*8 + u4 + 4)*64 + ln] = vl;
        }
        if (tid < 128) gs[tid] = g[(cc << 7) + tid];
        __syncthreads();

#pragma unroll
        for (int tt = 0; tt < 4; ++tt) {
            const f16x8* fb = Ef + tt*512 + lane;   // frag u at fb[u*64]
            f32x16 a0 = {}, a1 = {}, a2 = {};
#pragma unroll
            for (int s = 0; s < 4; ++s) {
                f16x8 eh = fb[s*64];
                a0 = __builtin_amdgcn_mfma_f32_32x32x16_f16(eh, xh[s], a0, 0, 0, 0);
                a1 = __builtin_amdgcn_mfma_f32_32x32x16_f16(eh, xl[s], a1, 0, 0, 0);
                f16x8 el = fb[(4+s)*64];
                a1 = __builtin_amdgcn_mfma_f32_32x32x16_f16(el, xh[s], a1, 0, 0, 0);
                a2 = __builtin_amdgcn_mfma_f32_32x32x16_f16(el, xl[s], a2, 0, 0, 0);
            }
            // ---- distances: m = dot + g[code]; maximize (== argmin dist) ----
            const int kbase = (((cc << 2) + tt) << 5);
            float4 g0 = *reinterpret_cast<const float4*>(&gs[tt*32      + 4*hi]);
            float4 g1 = *reinterpret_cast<const float4*>(&gs[tt*32 + 8  + 4*hi]);
            float4 g2 = *reinterpret_cast<const float4*>(&gs[tt*32 + 16 + 4*hi]);
            float4 g3 = *reinterpret_cast<const float4*>(&gs[tt*32 + 24 + 4*hi]);
#pragma unroll
            for (int r = 0; r < 16; ++r) {
                float m = fmaf(a2[r], c2, fmaf(a1[r], c1, a0[r]));
                float gg;
                switch (r >> 2) {
                    case 0: gg = (r&3)==0?g0.x:(r&3)==1?g0.y:(r&3)==2?g0.z:g0.w; break;
                    case 1: gg = (r&3)==0?g1.x:(r&3)==1?g1.y:(r&3)==2?g1.z:g1.w; break;
                    case 2: gg = (r&3)==0?g2.x:(r&3)==1?g2.y:(r&3)==2?g2.z:g2.w; break;
                    default:gg = (r&3)==0?g3.x:(r&3)==1?g3.y:(r&3)==2?g3.z:g3.w; break;
                }
                m += gg;
                // code rows ascend with r within this lane -> strict > = first-min
                int code = kbase + (r & 3) + ((r >> 2) << 3) + (hi << 2);
                if (m > bestm) { bestm = m; bestk = code; }
            }
        }
        __syncthreads();   // before next chunk overwrites Ef
    }

    // ---- merge the two half-wave candidates for each query column ----
    {
        float ob = __shfl_xor(bestm, 32, 64);
        int   oi = __shfl_xor(bestk, 32, 64);
        if (ob > bestm || (ob == bestm && oi < bestk)) { bestm = ob; bestk = oi; }
    }

    // ---- indices (as float) + histogram ----
    if (hi == 0) {
        out_idx[q] = (float)bestk;
        atomicAdd(&counts[bestk], 1u);
    }

    // ---- quantized (B,C,H,W): gather emb row (L2-hot), coalesced stores ----
    const float* er = emb + ((size_t)bestk << 6);
    float* ob_ = out_q + ((size_t)b << 18) + hw0 + col;
#pragma unroll
    for (int c4 = 0; c4 < 32; ++c4) {
        int c = hi*32 + c4;
        ob_[(size_t)c << 12] = er[c];
    }
}

__global__ __launch_bounds__(1024) void vq_perp(const unsigned int* __restrict__ counts,
                                                float* __restrict__ out_p) {
    __shared__ float red[16];
    int tid = threadIdx.x;  // 1024
    float p = (float)counts[tid] * (1.0f / (float)NTOT);
    float t = p * logf(p + 1e-10f);
#pragma unroll
    for (int m = 1; m < 64; m <<= 1) t += __shfl_xor(t, m, 64);
    if ((tid & 63) == 0) red[tid >> 6] = t;
    __syncthreads();
    if (tid < 16) {
        float s = red[tid];
#pragma unroll
        for (int m = 1; m < 16; m <<= 1) s += __shfl_xor(s, m, 64);
        if (tid == 0) out_p[0] = expf(-s);
    }
}

extern "C" void kernel_launch(void* const* d_in, const int* in_sizes, int n_in,
                              void* d_out, int out_size, void* d_ws, size_t ws_size,
                              hipStream_t stream) {
    const float* in  = (const float*)d_in[0];   // (32, 64, 64, 64)
    const float* emb = (const float*)d_in[1];   // (1024, 64)
    float* out = (float*)d_out;

    unsigned int* counts = (unsigned int*)d_ws;
    float* g = (float*)d_ws + NK;

    float* out_idx = out;                       // 131072
    float* out_q   = out + NTOT;                // 8388608
    float* out_p   = out + NTOT + (size_t)NTOT * ND;  // 1

    vq_prep<<<1, 1024, 0, stream>>>(emb, counts, g);
    vq_main<<<512, 512, 0, stream>>>(in, emb, g, counts, out_idx, out_q);
    vq_perp<<<1, 1024, 0, stream>>>(counts, out_p);
}